// Round 19
// baseline (351.555 us; speedup 1.0000x reference)
//
#include <hip/hip_runtime.h>
#include <hip/hip_bf16.h>
#include <math.h>

typedef __attribute__((ext_vector_type(8))) short short8v;
typedef __attribute__((ext_vector_type(4))) float f32x4;
typedef __attribute__((ext_vector_type(16))) float f32x16;
typedef __attribute__((ext_vector_type(2))) unsigned uint2v;

#define NB 64
#define CC 64
#define TT 300
#define VV 25
#define SS 3
#define TB 4
#define TBLK (TT/TB)   // 75
#define TILES (NB*TBLK)          // 4800
#define TOTAL4 (NB*CC*TT*VV/4)   // 7,680,000
#define PERC4  (TT*VV/4)         // 1875
#define CNTF   480000.0f

// ws layout:
//   floats [n*128 + o] per-n sum, [n*128+64+o] per-n sumsq  -> [0..8192)
//   floats [8192+o] scale, [8256+o] shift
//   byte 36864: A-hat 32x32 B-frags [s][ksv][lane] 16B  (6*1024 = 6144 B)
//   byte 49152: Wc 32x32 A-frags [s][ot][ks][lane] 16B  (24*1024 = 24576 B)
//   byte 131072: unnormalized-y bf16 buffer (61.44 MB)
#define AFA_BYTES 36864
#define WCF_BYTES 49152
#define YOFF_BYTES 131072

static __device__ __forceinline__ unsigned short f2bf(float f){
    union { __hip_bfloat16 h; unsigned short s; } u;
    u.h = __float2bfloat16(f);
    return u.s;
}
static __device__ __forceinline__ float bf2f(unsigned short b){
    return __uint_as_float(((unsigned)b) << 16);
}
static __device__ __forceinline__ void packq(float z0, float z1, float z2, float z3,
                                             unsigned& d0, unsigned& d1){
    d0 = (unsigned)f2bf(z0) | ((unsigned)f2bf(z1) << 16);
    d1 = (unsigned)f2bf(z2) | ((unsigned)f2bf(z3) << 16);
}
static __device__ __forceinline__ short8v mk8(unsigned q0,unsigned q1,unsigned q2,unsigned q3){
    union { unsigned u[4]; short8v v; } x;
    x.u[0]=q0; x.u[1]=q1; x.u[2]=q2; x.u[3]=q3;
    return x.v;
}

// permlane32_swap(A,B): A' = [A.lo | B.lo], B' = [A.hi | B.hi]
#if __has_builtin(__builtin_amdgcn_permlane32_swap)
#define SWAP32(a,b,ra,rb) { uint2v _r = __builtin_amdgcn_permlane32_swap((a),(b),false,false); (ra)=_r[0]; (rb)=_r[1]; }
#else
#define SWAP32(a,b,ra,rb) { unsigned _sa=(unsigned)__shfl_xor((int)(a),32); \
                            unsigned _sb=(unsigned)__shfl_xor((int)(b),32); \
                            (ra) = hi ? _sb : (a); (rb) = hi ? (b) : _sa; }
#endif

// 8 blocks x 384 threads: zero stats slices; block 0 builds fragment tables.
__global__ void gcn_prep(const float* __restrict__ PA, const float* __restrict__ Wc,
                         float* __restrict__ ws)
{
    __shared__ float inv[SS][VV];
    const int tid = threadIdx.x;
    const int nz = 8192 / 8;
    for (int i = tid; i < nz; i += 384) ws[blockIdx.x * nz + i] = 0.f;
    if (blockIdx.x != 0) return;

    if (tid < SS*VV){
        int s = tid/VV, w = tid%VV;
        float sum = 0.f;
        for (int v=0; v<VV; ++v){ float p = PA[s*VV*VV + v*VV + w]; sum = fmaf(p,p,sum); }
        inv[s][w] = 1.f/(sqrtf(sum)+1e-4f);
    }
    __syncthreads();
    {   // A-hat 32x32 B-fragments: fid = s*2+ksv (6 frags x 64 lanes = 384 threads)
        int fid = tid >> 6, lane = tid & 63;
        int s = fid >> 1, ksv = fid & 1;
        int w = lane & 31, h = lane >> 5;
        int v0 = 16*ksv + 8*h;
        short8v vals;
        #pragma unroll
        for (int j=0;j<8;++j){
            int v = v0 + j;
            float f = (v<VV && w<VV) ? PA[s*VV*VV + v*VV + w]*inv[s][w] : 0.f;
            vals[j] = (short)f2bf(f);
        }
        *(short8v*)((char*)ws + AFA_BYTES + (size_t)(fid*64 + lane)*16) = vals;
    }
    // Wc 32x32 A-fragments: fid = ((s*2+ot)*4+ks), 24 frags
    for (int fid4 = tid; fid4 < SS*2*4*64; fid4 += 384){
        int lane = fid4 & 63;
        int ks = (fid4 >> 6) & 3;
        int ot = (fid4 >> 8) & 1;
        int s  = fid4 >> 9;
        int o  = 32*ot + (lane & 31);
        int c0 = 16*ks + 8*(lane >> 5);
        short8v vals;
        #pragma unroll
        for (int j=0;j<8;++j) vals[j] = (short)f2bf(Wc[((size_t)s*CC + o)*CC + c0 + j]);
        *(short8v*)((char*)ws + WCF_BYTES + (size_t)fid4*16) = vals;
    }
}

template<bool YB>
__global__ __launch_bounds__(256,4) void gcn_main_kernel(
    const float* __restrict__ x, float* __restrict__ ws,
    float* __restrict__ yf32, __hip_bfloat16* __restrict__ ybf)
{
    // ONLY LDS: 12.8 KB y tile [o][100] bf16 (epilogue only)
    __shared__ __align__(16) unsigned short lds[CC*100];

    const int tid  = threadIdx.x;
    const int lane = tid & 63;
    const int wv   = tid >> 6;                 // wave owns t = t0 + wv
    const int l31  = lane & 31, h = lane >> 5;
    const bool hi  = (lane >= 32);
    (void)hi;
    const int n    = blockIdx.x / TBLK;
    const int t0   = (blockIdx.x % TBLK) * TB;
    const int t    = t0 + wv;

    // x A-fragments (32x32x16): rows c = 32mt+l31, k v = 16ksv + 8h + j
    short8v axf[2][2];
    #pragma unroll
    for (int mt=0; mt<2; ++mt){
        #pragma unroll
        for (int ksv=0; ksv<2; ++ksv){
            const int c  = 32*mt + l31;
            const int v0 = 16*ksv + 8*h;
            const float* p = x + ((size_t)(n*CC + c)*TT + t)*VV + v0;
            short8v f;
            if (v0 < 24){
                float4 a = *(const float4*)p;
                float4 b = *(const float4*)(p+4);
                f[0]=(short)f2bf(a.x); f[1]=(short)f2bf(a.y); f[2]=(short)f2bf(a.z); f[3]=(short)f2bf(a.w);
                f[4]=(short)f2bf(b.x); f[5]=(short)f2bf(b.y); f[6]=(short)f2bf(b.z); f[7]=(short)f2bf(b.w);
            } else {
                f[0]=(short)f2bf(p[0]);   // v=24 only
                f[1]=0; f[2]=0; f[3]=0; f[4]=0; f[5]=0; f[6]=0; f[7]=0;
            }
            axf[mt][ksv] = f;
        }
    }

    const short8v* afrag = (const short8v*)((const char*)ws + AFA_BYTES);
    const short8v* wfrag = (const short8v*)((const char*)ws + WCF_BYTES);

    // hoist ALL A-hat fragments pre-loop: their L1/L2 latency overlaps the
    // x-gather window instead of stalling each s iteration (+24 regs, fits)
    short8v afA[SS][2];
    #pragma unroll
    for (int s=0; s<SS; ++s){
        afA[s][0] = afrag[(s*2+0)*64 + lane];
        afA[s][1] = afrag[(s*2+1)*64 + lane];
    }

    f32x16 zf16;
    #pragma unroll
    for (int i=0;i<16;++i) zf16[i] = 0.f;
    f32x16 yacc[2];
    yacc[0] = zf16; yacc[1] = zf16;

    #pragma unroll 1
    for (int s=0; s<SS; ++s){
        // stage A: Z[mt] (c=32mt..32mt+31, w) — 2 chained MFMA over v
        unsigned pk[2][4][2];   // [mt][group q][dword]
        #pragma unroll
        for (int mt=0; mt<2; ++mt){
            f32x16 z = __builtin_amdgcn_mfma_f32_32x32x16_bf16(axf[mt][0], afA[s][0], zf16, 0,0,0);
            z = __builtin_amdgcn_mfma_f32_32x32x16_bf16(axf[mt][1], afA[s][1], z, 0,0,0);
            #pragma unroll
            for (int q=0; q<4; ++q)
                packq(z[4*q], z[4*q+1], z[4*q+2], z[4*q+3], pk[mt][q][0], pk[mt][q][1]);
        }

        // transpose via permlane32_swap + stage B (no DS ops)
        #pragma unroll
        for (int mt=0; mt<2; ++mt){
            #pragma unroll
            for (int ksl=0; ksl<2; ++ksl){
                const int ks = 2*mt + ksl;
                unsigned r0d0, r1d0, r0d1, r1d1;
                SWAP32(pk[mt][2*ksl][0],   pk[mt][2*ksl+1][0], r0d0, r1d0);
                SWAP32(pk[mt][2*ksl][1],   pk[mt][2*ksl+1][1], r0d1, r1d1);
                short8v bz = mk8(r0d0, r0d1, r1d0, r1d1);
                #pragma unroll
                for (int ot=0; ot<2; ++ot){
                    short8v wc = wfrag[((s*2+ot)*4+ks)*64 + lane];
                    yacc[ot] = __builtin_amdgcn_mfma_f32_32x32x16_bf16(wc, bz, yacc[ot], 0,0,0);
                }
            }
        }
    }

    // epilogue: y -> LDS tile [o][t_loc*25+w] bf16 (32x32 C/D layout)
    #pragma unroll
    for (int ot=0; ot<2; ++ot){
        #pragma unroll
        for (int r=0; r<16; ++r){
            const int o = 32*ot + (r&3) + 8*(r>>2) + 4*h;
            if (l31 < VV)
                lds[o*100 + wv*25 + l31] = f2bf(yacc[ot][r]);
        }
    }
    __syncthreads();

    // coalesced global store: 64 rows x 200 B, thread-linear uint2
    // (conv bias cancels through training-mode BN — omitted)
    for (int i = tid; i < 1600; i += 256){
        const int row = i / 25;          // o
        const int c8  = i % 25;          // 4-short grain within 100 cols
        uint2 d = *(const uint2*)&lds[row*100 + c8*4];
        const size_t base = (size_t)(n*CC + row)*(TT*VV) + (size_t)t0*VV + c8*4;
        if (YB){
            *(uint2*)((unsigned short*)ybf + base) = d;
        } else {
            float4 f;
            f.x = bf2f((unsigned short)(d.x & 0xffff));
            f.y = bf2f((unsigned short)(d.x >> 16));
            f.z = bf2f((unsigned short)(d.y & 0xffff));
            f.w = bf2f((unsigned short)(d.y >> 16));
            *(float4*)(yf32 + base) = f;
        }
    }

    // fused stats: thread (o = tid>>2, q = tid&3) reads b64 grains q, q+4, ...
    {
        const int o = tid >> 2, q = tid & 3;
        float s1 = 0.f, s2 = 0.f;
        for (int gr = q; gr < 25; gr += 4){
            uint2 d = *(const uint2*)&lds[o*100 + gr*4];
            float a0 = bf2f((unsigned short)(d.x & 0xffff));
            float a1 = bf2f((unsigned short)(d.x >> 16));
            float a2 = bf2f((unsigned short)(d.y & 0xffff));
            float a3 = bf2f((unsigned short)(d.y >> 16));
            s1 += (a0+a1)+(a2+a3);
            s2 = fmaf(a0,a0,fmaf(a1,a1,fmaf(a2,a2,fmaf(a3,a3,s2))));
        }
        s1 += __shfl_xor(s1,1); s1 += __shfl_xor(s1,2);
        s2 += __shfl_xor(s2,1); s2 += __shfl_xor(s2,2);
        if (q == 0){
            atomicAdd(&ws[n*128 + o],      s1);
            atomicAdd(&ws[n*128 + 64 + o], s2);
        }
    }
}

__global__ void gcn_finalize_kernel(const float* __restrict__ gamma,
                                    const float* __restrict__ beta,
                                    float* __restrict__ ws)
{
    const int o = threadIdx.x;
    if (o < CC) {
        float s = 0.f, q = 0.f;
        for (int n = 0; n < NB; ++n){
            s += ws[n*128 + o];
            q += ws[n*128 + 64 + o];
        }
        const float mean = s / CNTF;
        const float var  = q / CNTF - mean * mean;
        const float sc   = gamma[o] * rsqrtf(var + 1e-5f);
        ws[8192 + o] = sc;
        ws[8256 + o] = beta[o] - mean * sc;
    }
}

template<bool YB>
__global__ __launch_bounds__(256) void gcn_bn_relu_kernel(
    const float* __restrict__ x, float* __restrict__ out,
    const float* __restrict__ ws, const unsigned short* __restrict__ ybf)
{
    for (int i = blockIdx.x * 256 + threadIdx.x; i < TOTAL4; i += gridDim.x * 256) {
        const int c = (i / PERC4) & (CC - 1);
        const float sc = ws[8192 + c];
        const float sh = ws[8256 + c];
        float4 yv;
        if (YB){
            uint2 yb = *(const uint2*)&ybf[4*i];
            yv.x = bf2f((unsigned short)(yb.x & 0xffff));
            yv.y = bf2f((unsigned short)(yb.x >> 16));
            yv.z = bf2f((unsigned short)(yb.y & 0xffff));
            yv.w = bf2f((unsigned short)(yb.y >> 16));
        } else {
            yv = reinterpret_cast<float4*>(out)[i];
        }
        float4 xv = reinterpret_cast<const float4*>(x)[i];
        f32x4 r;
        r[0] = fmaxf(fmaf(yv.x, sc, sh) + xv.x, 0.f);
        r[1] = fmaxf(fmaf(yv.y, sc, sh) + xv.y, 0.f);
        r[2] = fmaxf(fmaf(yv.z, sc, sh) + xv.z, 0.f);
        r[3] = fmaxf(fmaf(yv.w, sc, sh) + xv.w, 0.f);
        // out is never re-read: bypass L2/L3 to preserve residency for x/ybf reads
        __builtin_nontemporal_store(r, (f32x4*)out + i);
    }
}

extern "C" void kernel_launch(void* const* d_in, const int* in_sizes, int n_in,
                              void* d_out, int out_size, void* d_ws, size_t ws_size,
                              hipStream_t stream)
{
    const float* x     = (const float*)d_in[0];
    const float* PA    = (const float*)d_in[1];
    const float* Wc    = (const float*)d_in[2];
    const float* gamma = (const float*)d_in[4];
    const float* beta  = (const float*)d_in[5];
    float* out = (float*)d_out;
    float* ws  = (float*)d_ws;

    const size_t ybytes = (size_t)NB*CC*TT*VV*2;
    const bool yb = ws_size >= (size_t)YOFF_BYTES + ybytes;
    __hip_bfloat16* ybf = (__hip_bfloat16*)((char*)d_ws + YOFF_BYTES);

    gcn_prep<<<8, 384, 0, stream>>>(PA, Wc, ws);
    if (yb){
        gcn_main_kernel<true><<<TILES, 256, 0, stream>>>(x, ws, out, ybf);
        gcn_finalize_kernel<<<1, 64, 0, stream>>>(gamma, beta, ws);
        gcn_bn_relu_kernel<true><<<4096, 256, 0, stream>>>(x, out, ws, (const unsigned short*)ybf);
    } else {
        gcn_main_kernel<false><<<TILES, 256, 0, stream>>>(x, ws, out, ybf);
        gcn_finalize_kernel<<<1, 64, 0, stream>>>(gamma, beta, ws);
        gcn_bn_relu_kernel<false><<<4096, 256, 0, stream>>>(x, out, ws, (const unsigned short*)ybf);
    }
}

// Round 20
// 115.026 us; speedup vs baseline: 3.0563x; 3.0563x over previous
//
#include <hip/hip_runtime.h>
#include <hip/hip_bf16.h>
#include <math.h>

typedef __attribute__((ext_vector_type(8))) short short8v;
typedef __attribute__((ext_vector_type(4))) float f32x4;
typedef __attribute__((ext_vector_type(16))) float f32x16;
typedef __attribute__((ext_vector_type(2))) unsigned uint2v;

#define NB 64
#define CC 64
#define TT 300
#define VV 25
#define SS 3
#define TB 4
#define TBLK (TT/TB)   // 75
#define TILES (NB*TBLK)          // 4800
#define TOTAL4 (NB*CC*TT*VV/4)   // 7,680,000
#define PERC4  (TT*VV/4)         // 1875
#define CNTF   480000.0f

// ws layout:
//   floats [n*128 + o] per-n sum, [n*128+64+o] per-n sumsq  -> [0..8192)
//   floats [8192+o] scale, [8256+o] shift
//   byte 36864: A-hat 32x32 B-frags [s][ksv][lane] 16B  (6*1024 = 6144 B)
//   byte 49152: Wc 32x32 A-frags [s][ot][ks][lane] 16B  (24*1024 = 24576 B)
//   byte 131072: unnormalized-y bf16 buffer (61.44 MB)
#define AFA_BYTES 36864
#define WCF_BYTES 49152
#define YOFF_BYTES 131072

static __device__ __forceinline__ unsigned short f2bf(float f){
    union { __hip_bfloat16 h; unsigned short s; } u;
    u.h = __float2bfloat16(f);
    return u.s;
}
static __device__ __forceinline__ float bf2f(unsigned short b){
    return __uint_as_float(((unsigned)b) << 16);
}
static __device__ __forceinline__ void packq(float z0, float z1, float z2, float z3,
                                             unsigned& d0, unsigned& d1){
    d0 = (unsigned)f2bf(z0) | ((unsigned)f2bf(z1) << 16);
    d1 = (unsigned)f2bf(z2) | ((unsigned)f2bf(z3) << 16);
}
static __device__ __forceinline__ short8v mk8(unsigned q0,unsigned q1,unsigned q2,unsigned q3){
    union { unsigned u[4]; short8v v; } x;
    x.u[0]=q0; x.u[1]=q1; x.u[2]=q2; x.u[3]=q3;
    return x.v;
}

// permlane32_swap(A,B): A' = [A.lo | B.lo], B' = [A.hi | B.hi]
#if __has_builtin(__builtin_amdgcn_permlane32_swap)
#define SWAP32(a,b,ra,rb) { uint2v _r = __builtin_amdgcn_permlane32_swap((a),(b),false,false); (ra)=_r[0]; (rb)=_r[1]; }
#else
#define SWAP32(a,b,ra,rb) { unsigned _sa=(unsigned)__shfl_xor((int)(a),32); \
                            unsigned _sb=(unsigned)__shfl_xor((int)(b),32); \
                            (ra) = hi ? _sb : (a); (rb) = hi ? (b) : _sa; }
#endif

// 8 blocks x 384 threads: zero stats slices; block 0 builds fragment tables.
__global__ void gcn_prep(const float* __restrict__ PA, const float* __restrict__ Wc,
                         float* __restrict__ ws)
{
    __shared__ float inv[SS][VV];
    const int tid = threadIdx.x;
    const int nz = 8192 / 8;
    for (int i = tid; i < nz; i += 384) ws[blockIdx.x * nz + i] = 0.f;
    if (blockIdx.x != 0) return;

    if (tid < SS*VV){
        int s = tid/VV, w = tid%VV;
        float sum = 0.f;
        for (int v=0; v<VV; ++v){ float p = PA[s*VV*VV + v*VV + w]; sum = fmaf(p,p,sum); }
        inv[s][w] = 1.f/(sqrtf(sum)+1e-4f);
    }
    __syncthreads();
    {   // A-hat 32x32 B-fragments: fid = s*2+ksv (6 frags x 64 lanes = 384 threads)
        int fid = tid >> 6, lane = tid & 63;
        int s = fid >> 1, ksv = fid & 1;
        int w = lane & 31, h = lane >> 5;
        int v0 = 16*ksv + 8*h;
        short8v vals;
        #pragma unroll
        for (int j=0;j<8;++j){
            int v = v0 + j;
            float f = (v<VV && w<VV) ? PA[s*VV*VV + v*VV + w]*inv[s][w] : 0.f;
            vals[j] = (short)f2bf(f);
        }
        *(short8v*)((char*)ws + AFA_BYTES + (size_t)(fid*64 + lane)*16) = vals;
    }
    // Wc 32x32 A-fragments: fid = ((s*2+ot)*4+ks), 24 frags
    for (int fid4 = tid; fid4 < SS*2*4*64; fid4 += 384){
        int lane = fid4 & 63;
        int ks = (fid4 >> 6) & 3;
        int ot = (fid4 >> 8) & 1;
        int s  = fid4 >> 9;
        int o  = 32*ot + (lane & 31);
        int c0 = 16*ks + 8*(lane >> 5);
        short8v vals;
        #pragma unroll
        for (int j=0;j<8;++j) vals[j] = (short)f2bf(Wc[((size_t)s*CC + o)*CC + c0 + j]);
        *(short8v*)((char*)ws + WCF_BYTES + (size_t)fid4*16) = vals;
    }
}

template<bool YB>
__global__ __launch_bounds__(256,4) void gcn_main_kernel(
    const float* __restrict__ x, float* __restrict__ ws,
    float* __restrict__ yf32, __hip_bfloat16* __restrict__ ybf)
{
    // ONLY LDS: 12.8 KB y tile [o][100] bf16 (epilogue only)
    __shared__ __align__(16) unsigned short lds[CC*100];

    const int tid  = threadIdx.x;
    const int lane = tid & 63;
    const int wv   = tid >> 6;                 // wave owns t = t0 + wv
    const int l31  = lane & 31, h = lane >> 5;
    const bool hi  = (lane >= 32);
    (void)hi;
    const int n    = blockIdx.x / TBLK;
    const int t0   = (blockIdx.x % TBLK) * TB;
    const int t    = t0 + wv;

    // x A-fragments (32x32x16): rows c = 32mt+l31, k v = 16ksv + 8h + j
    short8v axf[2][2];
    #pragma unroll
    for (int mt=0; mt<2; ++mt){
        #pragma unroll
        for (int ksv=0; ksv<2; ++ksv){
            const int c  = 32*mt + l31;
            const int v0 = 16*ksv + 8*h;
            const float* p = x + ((size_t)(n*CC + c)*TT + t)*VV + v0;
            short8v f;
            if (v0 < 24){
                float4 a = *(const float4*)p;
                float4 b = *(const float4*)(p+4);
                f[0]=(short)f2bf(a.x); f[1]=(short)f2bf(a.y); f[2]=(short)f2bf(a.z); f[3]=(short)f2bf(a.w);
                f[4]=(short)f2bf(b.x); f[5]=(short)f2bf(b.y); f[6]=(short)f2bf(b.z); f[7]=(short)f2bf(b.w);
            } else {
                f[0]=(short)f2bf(p[0]);   // v=24 only
                f[1]=0; f[2]=0; f[3]=0; f[4]=0; f[5]=0; f[6]=0; f[7]=0;
            }
            axf[mt][ksv] = f;
        }
    }

    const short8v* afrag = (const short8v*)((const char*)ws + AFA_BYTES);
    const short8v* wfrag = (const short8v*)((const char*)ws + WCF_BYTES);

    f32x16 zf16;
    #pragma unroll
    for (int i=0;i<16;++i) zf16[i] = 0.f;
    f32x16 yacc[2];
    yacc[0] = zf16; yacc[1] = zf16;

    #pragma unroll 1
    for (int s=0; s<SS; ++s){
        short8v aA0 = afrag[(s*2+0)*64 + lane];
        short8v aA1 = afrag[(s*2+1)*64 + lane];

        // stage A: Z[mt] (c=32mt..32mt+31, w) — 2 chained MFMA over v
        unsigned pk[2][4][2];   // [mt][group q][dword]
        #pragma unroll
        for (int mt=0; mt<2; ++mt){
            f32x16 z = __builtin_amdgcn_mfma_f32_32x32x16_bf16(axf[mt][0], aA0, zf16, 0,0,0);
            z = __builtin_amdgcn_mfma_f32_32x32x16_bf16(axf[mt][1], aA1, z, 0,0,0);
            #pragma unroll
            for (int q=0; q<4; ++q)
                packq(z[4*q], z[4*q+1], z[4*q+2], z[4*q+3], pk[mt][q][0], pk[mt][q][1]);
        }

        // transpose via permlane32_swap + stage B (no DS ops)
        #pragma unroll
        for (int mt=0; mt<2; ++mt){
            #pragma unroll
            for (int ksl=0; ksl<2; ++ksl){
                const int ks = 2*mt + ksl;
                unsigned r0d0, r1d0, r0d1, r1d1;
                SWAP32(pk[mt][2*ksl][0],   pk[mt][2*ksl+1][0], r0d0, r1d0);
                SWAP32(pk[mt][2*ksl][1],   pk[mt][2*ksl+1][1], r0d1, r1d1);
                short8v bz = mk8(r0d0, r0d1, r1d0, r1d1);
                #pragma unroll
                for (int ot=0; ot<2; ++ot){
                    short8v wc = wfrag[((s*2+ot)*4+ks)*64 + lane];
                    yacc[ot] = __builtin_amdgcn_mfma_f32_32x32x16_bf16(wc, bz, yacc[ot], 0,0,0);
                }
            }
        }
    }

    // epilogue: y -> LDS tile [o][t_loc*25+w] bf16 (32x32 C/D layout)
    #pragma unroll
    for (int ot=0; ot<2; ++ot){
        #pragma unroll
        for (int r=0; r<16; ++r){
            const int o = 32*ot + (r&3) + 8*(r>>2) + 4*h;
            if (l31 < VV)
                lds[o*100 + wv*25 + l31] = f2bf(yacc[ot][r]);
        }
    }
    __syncthreads();

    // coalesced global store: 64 rows x 200 B, thread-linear uint2
    // (conv bias cancels through training-mode BN — omitted)
    for (int i = tid; i < 1600; i += 256){
        const int row = i / 25;          // o
        const int c8  = i % 25;          // 4-short grain within 100 cols
        uint2 d = *(const uint2*)&lds[row*100 + c8*4];
        const size_t base = (size_t)(n*CC + row)*(TT*VV) + (size_t)t0*VV + c8*4;
        if (YB){
            *(uint2*)((unsigned short*)ybf + base) = d;
        } else {
            float4 f;
            f.x = bf2f((unsigned short)(d.x & 0xffff));
            f.y = bf2f((unsigned short)(d.x >> 16));
            f.z = bf2f((unsigned short)(d.y & 0xffff));
            f.w = bf2f((unsigned short)(d.y >> 16));
            *(float4*)(yf32 + base) = f;
        }
    }

    // fused stats: thread (o = tid>>2, q = tid&3) reads b64 grains q, q+4, ...
    {
        const int o = tid >> 2, q = tid & 3;
        float s1 = 0.f, s2 = 0.f;
        for (int gr = q; gr < 25; gr += 4){
            uint2 d = *(const uint2*)&lds[o*100 + gr*4];
            float a0 = bf2f((unsigned short)(d.x & 0xffff));
            float a1 = bf2f((unsigned short)(d.x >> 16));
            float a2 = bf2f((unsigned short)(d.y & 0xffff));
            float a3 = bf2f((unsigned short)(d.y >> 16));
            s1 += (a0+a1)+(a2+a3);
            s2 = fmaf(a0,a0,fmaf(a1,a1,fmaf(a2,a2,fmaf(a3,a3,s2))));
        }
        s1 += __shfl_xor(s1,1); s1 += __shfl_xor(s1,2);
        s2 += __shfl_xor(s2,1); s2 += __shfl_xor(s2,2);
        if (q == 0){
            atomicAdd(&ws[n*128 + o],      s1);
            atomicAdd(&ws[n*128 + 64 + o], s2);
        }
    }
}

__global__ void gcn_finalize_kernel(const float* __restrict__ gamma,
                                    const float* __restrict__ beta,
                                    float* __restrict__ ws)
{
    const int o = threadIdx.x;
    if (o < CC) {
        float s = 0.f, q = 0.f;
        for (int n = 0; n < NB; ++n){
            s += ws[n*128 + o];
            q += ws[n*128 + 64 + o];
        }
        const float mean = s / CNTF;
        const float var  = q / CNTF - mean * mean;
        const float sc   = gamma[o] * rsqrtf(var + 1e-5f);
        ws[8192 + o] = sc;
        ws[8256 + o] = beta[o] - mean * sc;
    }
}

template<bool YB>
__global__ __launch_bounds__(256) void gcn_bn_relu_kernel(
    const float* __restrict__ x, float* __restrict__ out,
    const float* __restrict__ ws, const unsigned short* __restrict__ ybf)
{
    for (int i = blockIdx.x * 256 + threadIdx.x; i < TOTAL4; i += gridDim.x * 256) {
        const int c = (i / PERC4) & (CC - 1);
        const float sc = ws[8192 + c];
        const float sh = ws[8256 + c];
        float4 yv;
        if (YB){
            uint2 yb = *(const uint2*)&ybf[4*i];
            yv.x = bf2f((unsigned short)(yb.x & 0xffff));
            yv.y = bf2f((unsigned short)(yb.x >> 16));
            yv.z = bf2f((unsigned short)(yb.y & 0xffff));
            yv.w = bf2f((unsigned short)(yb.y >> 16));
        } else {
            yv = reinterpret_cast<float4*>(out)[i];
        }
        float4 xv = reinterpret_cast<const float4*>(x)[i];
        f32x4 r;
        r[0] = fmaxf(fmaf(yv.x, sc, sh) + xv.x, 0.f);
        r[1] = fmaxf(fmaf(yv.y, sc, sh) + xv.y, 0.f);
        r[2] = fmaxf(fmaf(yv.z, sc, sh) + xv.z, 0.f);
        r[3] = fmaxf(fmaf(yv.w, sc, sh) + xv.w, 0.f);
        // out is never re-read: bypass L2/L3 to preserve residency for x/ybf reads
        __builtin_nontemporal_store(r, (f32x4*)out + i);
    }
}

extern "C" void kernel_launch(void* const* d_in, const int* in_sizes, int n_in,
                              void* d_out, int out_size, void* d_ws, size_t ws_size,
                              hipStream_t stream)
{
    const float* x     = (const float*)d_in[0];
    const float* PA    = (const float*)d_in[1];
    const float* Wc    = (const float*)d_in[2];
    const float* gamma = (const float*)d_in[4];
    const float* beta  = (const float*)d_in[5];
    float* out = (float*)d_out;
    float* ws  = (float*)d_ws;

    const size_t ybytes = (size_t)NB*CC*TT*VV*2;
    const bool yb = ws_size >= (size_t)YOFF_BYTES + ybytes;
    __hip_bfloat16* ybf = (__hip_bfloat16*)((char*)d_ws + YOFF_BYTES);

    gcn_prep<<<8, 384, 0, stream>>>(PA, Wc, ws);
    if (yb){
        gcn_main_kernel<true><<<TILES, 256, 0, stream>>>(x, ws, out, ybf);
        gcn_finalize_kernel<<<1, 64, 0, stream>>>(gamma, beta, ws);
        gcn_bn_relu_kernel<true><<<4096, 256, 0, stream>>>(x, out, ws, (const unsigned short*)ybf);
    } else {
        gcn_main_kernel<false><<<TILES, 256, 0, stream>>>(x, ws, out, ybf);
        gcn_finalize_kernel<<<1, 64, 0, stream>>>(gamma, beta, ws);
        gcn_bn_relu_kernel<false><<<4096, 256, 0, stream>>>(x, out, ws, (const unsigned short*)ybf);
    }
}

// Round 21
// 108.941 us; speedup vs baseline: 3.2270x; 1.0559x over previous
//
#include <hip/hip_runtime.h>
#include <hip/hip_bf16.h>
#include <math.h>

typedef __attribute__((ext_vector_type(8))) short short8v;
typedef __attribute__((ext_vector_type(4))) float f32x4;
typedef __attribute__((ext_vector_type(16))) float f32x16;
typedef __attribute__((ext_vector_type(2))) unsigned uint2v;

#define NB 64
#define CC 64
#define TT 300
#define VV 25
#define SS 3
#define TB 4
#define TBLK (TT/TB)   // 75
#define TILES (NB*TBLK)          // 4800
#define TOTAL4 (NB*CC*TT*VV/4)   // 7,680,000
#define PERC4  (TT*VV/4)         // 1875
#define CNTF   480000.0f

// ws layout:
//   floats [n*128 + o] per-n sum, [n*128+64+o] per-n sumsq  -> [0..8192)
//   floats [8192+o] scale, [8256+o] shift
//   byte 36864: A-hat 32x32 B-frags [s][ksv][lane] 16B  (6*1024 = 6144 B)
//   byte 49152: Wc 32x32 A-frags [s][ot][ks][lane] 16B  (24*1024 = 24576 B)
//   byte 131072: unnormalized-y bf16 buffer (61.44 MB)
#define AFA_BYTES 36864
#define WCF_BYTES 49152
#define YOFF_BYTES 131072

static __device__ __forceinline__ unsigned short f2bf(float f){
    union { __hip_bfloat16 h; unsigned short s; } u;
    u.h = __float2bfloat16(f);
    return u.s;
}
static __device__ __forceinline__ float bf2f(unsigned short b){
    return __uint_as_float(((unsigned)b) << 16);
}
static __device__ __forceinline__ void packq(float z0, float z1, float z2, float z3,
                                             unsigned& d0, unsigned& d1){
    d0 = (unsigned)f2bf(z0) | ((unsigned)f2bf(z1) << 16);
    d1 = (unsigned)f2bf(z2) | ((unsigned)f2bf(z3) << 16);
}
static __device__ __forceinline__ short8v mk8(unsigned q0,unsigned q1,unsigned q2,unsigned q3){
    union { unsigned u[4]; short8v v; } x;
    x.u[0]=q0; x.u[1]=q1; x.u[2]=q2; x.u[3]=q3;
    return x.v;
}

// permlane32_swap(A,B): A' = [A.lo | B.lo], B' = [A.hi | B.hi]
#if __has_builtin(__builtin_amdgcn_permlane32_swap)
#define SWAP32(a,b,ra,rb) { uint2v _r = __builtin_amdgcn_permlane32_swap((a),(b),false,false); (ra)=_r[0]; (rb)=_r[1]; }
#else
#define SWAP32(a,b,ra,rb) { unsigned _sa=(unsigned)__shfl_xor((int)(a),32); \
                            unsigned _sb=(unsigned)__shfl_xor((int)(b),32); \
                            (ra) = hi ? _sb : (a); (rb) = hi ? (b) : _sa; }
#endif

// 8 blocks x 384 threads: zero stats slices; block 0 builds fragment tables.
__global__ void gcn_prep(const float* __restrict__ PA, const float* __restrict__ Wc,
                         float* __restrict__ ws)
{
    __shared__ float inv[SS][VV];
    const int tid = threadIdx.x;
    const int nz = 8192 / 8;
    for (int i = tid; i < nz; i += 384) ws[blockIdx.x * nz + i] = 0.f;
    if (blockIdx.x != 0) return;

    if (tid < SS*VV){
        int s = tid/VV, w = tid%VV;
        float sum = 0.f;
        for (int v=0; v<VV; ++v){ float p = PA[s*VV*VV + v*VV + w]; sum = fmaf(p,p,sum); }
        inv[s][w] = 1.f/(sqrtf(sum)+1e-4f);
    }
    __syncthreads();
    {   // A-hat 32x32 B-fragments: fid = s*2+ksv (6 frags x 64 lanes = 384 threads)
        int fid = tid >> 6, lane = tid & 63;
        int s = fid >> 1, ksv = fid & 1;
        int w = lane & 31, h = lane >> 5;
        int v0 = 16*ksv + 8*h;
        short8v vals;
        #pragma unroll
        for (int j=0;j<8;++j){
            int v = v0 + j;
            float f = (v<VV && w<VV) ? PA[s*VV*VV + v*VV + w]*inv[s][w] : 0.f;
            vals[j] = (short)f2bf(f);
        }
        *(short8v*)((char*)ws + AFA_BYTES + (size_t)(fid*64 + lane)*16) = vals;
    }
    // Wc 32x32 A-fragments: fid = ((s*2+ot)*4+ks), 24 frags
    for (int fid4 = tid; fid4 < SS*2*4*64; fid4 += 384){
        int lane = fid4 & 63;
        int ks = (fid4 >> 6) & 3;
        int ot = (fid4 >> 8) & 1;
        int s  = fid4 >> 9;
        int o  = 32*ot + (lane & 31);
        int c0 = 16*ks + 8*(lane >> 5);
        short8v vals;
        #pragma unroll
        for (int j=0;j<8;++j) vals[j] = (short)f2bf(Wc[((size_t)s*CC + o)*CC + c0 + j]);
        *(short8v*)((char*)ws + WCF_BYTES + (size_t)fid4*16) = vals;
    }
}

template<bool YB>
__global__ __launch_bounds__(256,4) void gcn_main_kernel(
    const float* __restrict__ x, float* __restrict__ ws,
    float* __restrict__ yf32, __hip_bfloat16* __restrict__ ybf)
{
    // ONLY LDS: 12.8 KB y tile [o][100] bf16 (epilogue only)
    __shared__ __align__(16) unsigned short lds[CC*100];

    const int tid  = threadIdx.x;
    const int lane = tid & 63;
    const int wv   = tid >> 6;                 // wave owns t = t0 + wv
    const int l31  = lane & 31, h = lane >> 5;
    const bool hi  = (lane >= 32);
    (void)hi;
    // XCD-aware bijective swizzle (T1): HW round-robins bid across 8 XCDs;
    // remap so each XCD serves a contiguous run of tiles (same-n blocks share
    // 1.92 MB of x rows -> concurrent hot set per XCD-L2 drops ~13n -> ~2n).
    // 4800 = 8 * 600 exactly, so (bid&7)*600 + (bid>>3) is a bijection.
    const int tile = (blockIdx.x & 7) * (TILES/8) + (blockIdx.x >> 3);
    const int n    = tile / TBLK;
    const int t0   = (tile % TBLK) * TB;
    const int t    = t0 + wv;

    // x A-fragments (32x32x16): rows c = 32mt+l31, k v = 16ksv + 8h + j
    short8v axf[2][2];
    #pragma unroll
    for (int mt=0; mt<2; ++mt){
        #pragma unroll
        for (int ksv=0; ksv<2; ++ksv){
            const int c  = 32*mt + l31;
            const int v0 = 16*ksv + 8*h;
            const float* p = x + ((size_t)(n*CC + c)*TT + t)*VV + v0;
            short8v f;
            if (v0 < 24){
                float4 a = *(const float4*)p;
                float4 b = *(const float4*)(p+4);
                f[0]=(short)f2bf(a.x); f[1]=(short)f2bf(a.y); f[2]=(short)f2bf(a.z); f[3]=(short)f2bf(a.w);
                f[4]=(short)f2bf(b.x); f[5]=(short)f2bf(b.y); f[6]=(short)f2bf(b.z); f[7]=(short)f2bf(b.w);
            } else {
                f[0]=(short)f2bf(p[0]);   // v=24 only
                f[1]=0; f[2]=0; f[3]=0; f[4]=0; f[5]=0; f[6]=0; f[7]=0;
            }
            axf[mt][ksv] = f;
        }
    }

    const short8v* afrag = (const short8v*)((const char*)ws + AFA_BYTES);
    const short8v* wfrag = (const short8v*)((const char*)ws + WCF_BYTES);

    f32x16 zf16;
    #pragma unroll
    for (int i=0;i<16;++i) zf16[i] = 0.f;
    f32x16 yacc[2];
    yacc[0] = zf16; yacc[1] = zf16;

    #pragma unroll 1
    for (int s=0; s<SS; ++s){
        short8v aA0 = afrag[(s*2+0)*64 + lane];
        short8v aA1 = afrag[(s*2+1)*64 + lane];

        // stage A: Z[mt] (c=32mt..32mt+31, w) — 2 chained MFMA over v
        unsigned pk[2][4][2];   // [mt][group q][dword]
        #pragma unroll
        for (int mt=0; mt<2; ++mt){
            f32x16 z = __builtin_amdgcn_mfma_f32_32x32x16_bf16(axf[mt][0], aA0, zf16, 0,0,0);
            z = __builtin_amdgcn_mfma_f32_32x32x16_bf16(axf[mt][1], aA1, z, 0,0,0);
            #pragma unroll
            for (int q=0; q<4; ++q)
                packq(z[4*q], z[4*q+1], z[4*q+2], z[4*q+3], pk[mt][q][0], pk[mt][q][1]);
        }

        // transpose via permlane32_swap + stage B (no DS ops)
        #pragma unroll
        for (int mt=0; mt<2; ++mt){
            #pragma unroll
            for (int ksl=0; ksl<2; ++ksl){
                const int ks = 2*mt + ksl;
                unsigned r0d0, r1d0, r0d1, r1d1;
                SWAP32(pk[mt][2*ksl][0],   pk[mt][2*ksl+1][0], r0d0, r1d0);
                SWAP32(pk[mt][2*ksl][1],   pk[mt][2*ksl+1][1], r0d1, r1d1);
                short8v bz = mk8(r0d0, r0d1, r1d0, r1d1);
                #pragma unroll
                for (int ot=0; ot<2; ++ot){
                    short8v wc = wfrag[((s*2+ot)*4+ks)*64 + lane];
                    yacc[ot] = __builtin_amdgcn_mfma_f32_32x32x16_bf16(wc, bz, yacc[ot], 0,0,0);
                }
            }
        }
    }

    // epilogue: y -> LDS tile [o][t_loc*25+w] bf16 (32x32 C/D layout)
    #pragma unroll
    for (int ot=0; ot<2; ++ot){
        #pragma unroll
        for (int r=0; r<16; ++r){
            const int o = 32*ot + (r&3) + 8*(r>>2) + 4*h;
            if (l31 < VV)
                lds[o*100 + wv*25 + l31] = f2bf(yacc[ot][r]);
        }
    }
    __syncthreads();

    // coalesced global store: 64 rows x 200 B, thread-linear uint2
    // (conv bias cancels through training-mode BN — omitted)
    for (int i = tid; i < 1600; i += 256){
        const int row = i / 25;          // o
        const int c8  = i % 25;          // 4-short grain within 100 cols
        uint2 d = *(const uint2*)&lds[row*100 + c8*4];
        const size_t base = (size_t)(n*CC + row)*(TT*VV) + (size_t)t0*VV + c8*4;
        if (YB){
            *(uint2*)((unsigned short*)ybf + base) = d;
        } else {
            float4 f;
            f.x = bf2f((unsigned short)(d.x & 0xffff));
            f.y = bf2f((unsigned short)(d.x >> 16));
            f.z = bf2f((unsigned short)(d.y & 0xffff));
            f.w = bf2f((unsigned short)(d.y >> 16));
            *(float4*)(yf32 + base) = f;
        }
    }

    // fused stats: thread (o = tid>>2, q = tid&3) reads b64 grains q, q+4, ...
    {
        const int o = tid >> 2, q = tid & 3;
        float s1 = 0.f, s2 = 0.f;
        for (int gr = q; gr < 25; gr += 4){
            uint2 d = *(const uint2*)&lds[o*100 + gr*4];
            float a0 = bf2f((unsigned short)(d.x & 0xffff));
            float a1 = bf2f((unsigned short)(d.x >> 16));
            float a2 = bf2f((unsigned short)(d.y & 0xffff));
            float a3 = bf2f((unsigned short)(d.y >> 16));
            s1 += (a0+a1)+(a2+a3);
            s2 = fmaf(a0,a0,fmaf(a1,a1,fmaf(a2,a2,fmaf(a3,a3,s2))));
        }
        s1 += __shfl_xor(s1,1); s1 += __shfl_xor(s1,2);
        s2 += __shfl_xor(s2,1); s2 += __shfl_xor(s2,2);
        if (q == 0){
            atomicAdd(&ws[n*128 + o],      s1);
            atomicAdd(&ws[n*128 + 64 + o], s2);
        }
    }
}

__global__ void gcn_finalize_kernel(const float* __restrict__ gamma,
                                    const float* __restrict__ beta,
                                    float* __restrict__ ws)
{
    const int o = threadIdx.x;
    if (o < CC) {
        float s = 0.f, q = 0.f;
        for (int n = 0; n < NB; ++n){
            s += ws[n*128 + o];
            q += ws[n*128 + 64 + o];
        }
        const float mean = s / CNTF;
        const float var  = q / CNTF - mean * mean;
        const float sc   = gamma[o] * rsqrtf(var + 1e-5f);
        ws[8192 + o] = sc;
        ws[8256 + o] = beta[o] - mean * sc;
    }
}

template<bool YB>
__global__ __launch_bounds__(256) void gcn_bn_relu_kernel(
    const float* __restrict__ x, float* __restrict__ out,
    const float* __restrict__ ws, const unsigned short* __restrict__ ybf)
{
    for (int i = blockIdx.x * 256 + threadIdx.x; i < TOTAL4; i += gridDim.x * 256) {
        const int c = (i / PERC4) & (CC - 1);
        const float sc = ws[8192 + c];
        const float sh = ws[8256 + c];
        float4 yv;
        if (YB){
            uint2 yb = *(const uint2*)&ybf[4*i];
            yv.x = bf2f((unsigned short)(yb.x & 0xffff));
            yv.y = bf2f((unsigned short)(yb.x >> 16));
            yv.z = bf2f((unsigned short)(yb.y & 0xffff));
            yv.w = bf2f((unsigned short)(yb.y >> 16));
        } else {
            yv = reinterpret_cast<float4*>(out)[i];
        }
        float4 xv = reinterpret_cast<const float4*>(x)[i];
        f32x4 r;
        r[0] = fmaxf(fmaf(yv.x, sc, sh) + xv.x, 0.f);
        r[1] = fmaxf(fmaf(yv.y, sc, sh) + xv.y, 0.f);
        r[2] = fmaxf(fmaf(yv.z, sc, sh) + xv.z, 0.f);
        r[3] = fmaxf(fmaf(yv.w, sc, sh) + xv.w, 0.f);
        // out is never re-read: bypass L2/L3 to preserve residency for x/ybf reads
        __builtin_nontemporal_store(r, (f32x4*)out + i);
    }
}

extern "C" void kernel_launch(void* const* d_in, const int* in_sizes, int n_in,
                              void* d_out, int out_size, void* d_ws, size_t ws_size,
                              hipStream_t stream)
{
    const float* x     = (const float*)d_in[0];
    const float* PA    = (const float*)d_in[1];
    const float* Wc    = (const float*)d_in[2];
    const float* gamma = (const float*)d_in[4];
    const float* beta  = (const float*)d_in[5];
    float* out = (float*)d_out;
    float* ws  = (float*)d_ws;

    const size_t ybytes = (size_t)NB*CC*TT*VV*2;
    const bool yb = ws_size >= (size_t)YOFF_BYTES + ybytes;
    __hip_bfloat16* ybf = (__hip_bfloat16*)((char*)d_ws + YOFF_BYTES);

    gcn_prep<<<8, 384, 0, stream>>>(PA, Wc, ws);
    if (yb){
        gcn_main_kernel<true><<<TILES, 256, 0, stream>>>(x, ws, out, ybf);
        gcn_finalize_kernel<<<1, 64, 0, stream>>>(gamma, beta, ws);
        gcn_bn_relu_kernel<true><<<4096, 256, 0, stream>>>(x, out, ws, (const unsigned short*)ybf);
    } else {
        gcn_main_kernel<false><<<TILES, 256, 0, stream>>>(x, ws, out, ybf);
        gcn_finalize_kernel<<<1, 64, 0, stream>>>(gamma, beta, ws);
        gcn_bn_relu_kernel<false><<<4096, 256, 0, stream>>>(x, out, ws, (const unsigned short*)ybf);
    }
}

// Round 22
// 108.873 us; speedup vs baseline: 3.2290x; 1.0006x over previous
//
#include <hip/hip_runtime.h>
#include <hip/hip_bf16.h>
#include <math.h>

typedef __attribute__((ext_vector_type(8))) short short8v;
typedef __attribute__((ext_vector_type(4))) float f32x4;
typedef __attribute__((ext_vector_type(16))) float f32x16;
typedef __attribute__((ext_vector_type(2))) unsigned uint2v;
typedef __attribute__((ext_vector_type(2))) unsigned uu2;

#define NB 64
#define CC 64
#define TT 300
#define VV 25
#define SS 3
#define TB 4
#define TBLK (TT/TB)   // 75
#define TILES (NB*TBLK)          // 4800
#define TOTAL4 (NB*CC*TT*VV/4)   // 7,680,000
#define PERC4  (TT*VV/4)         // 1875
#define CNTF   480000.0f

// ws layout:
//   floats [n*128 + o] per-n sum, [n*128+64+o] per-n sumsq  -> [0..8192)
//   byte 36864: A-hat 32x32 B-frags [s][ksv][lane] 16B  (6*1024 = 6144 B)
//   byte 49152: Wc 32x32 A-frags [s][ot][ks][lane] 16B  (24*1024 = 24576 B)
//   byte 131072: unnormalized-y bf16 buffer (61.44 MB)
#define AFA_BYTES 36864
#define WCF_BYTES 49152
#define YOFF_BYTES 131072

static __device__ __forceinline__ unsigned short f2bf(float f){
    union { __hip_bfloat16 h; unsigned short s; } u;
    u.h = __float2bfloat16(f);
    return u.s;
}
static __device__ __forceinline__ float bf2f(unsigned short b){
    return __uint_as_float(((unsigned)b) << 16);
}
static __device__ __forceinline__ void packq(float z0, float z1, float z2, float z3,
                                             unsigned& d0, unsigned& d1){
    d0 = (unsigned)f2bf(z0) | ((unsigned)f2bf(z1) << 16);
    d1 = (unsigned)f2bf(z2) | ((unsigned)f2bf(z3) << 16);
}
static __device__ __forceinline__ short8v mk8(unsigned q0,unsigned q1,unsigned q2,unsigned q3){
    union { unsigned u[4]; short8v v; } x;
    x.u[0]=q0; x.u[1]=q1; x.u[2]=q2; x.u[3]=q3;
    return x.v;
}

// permlane32_swap(A,B): A' = [A.lo | B.lo], B' = [A.hi | B.hi]
#if __has_builtin(__builtin_amdgcn_permlane32_swap)
#define SWAP32(a,b,ra,rb) { uint2v _r = __builtin_amdgcn_permlane32_swap((a),(b),false,false); (ra)=_r[0]; (rb)=_r[1]; }
#else
#define SWAP32(a,b,ra,rb) { unsigned _sa=(unsigned)__shfl_xor((int)(a),32); \
                            unsigned _sb=(unsigned)__shfl_xor((int)(b),32); \
                            (ra) = hi ? _sb : (a); (rb) = hi ? (b) : _sa; }
#endif

// 8 blocks x 384 threads: zero stats slices; block 0 builds fragment tables.
__global__ void gcn_prep(const float* __restrict__ PA, const float* __restrict__ Wc,
                         float* __restrict__ ws)
{
    __shared__ float inv[SS][VV];
    const int tid = threadIdx.x;
    const int nz = 8192 / 8;
    for (int i = tid; i < nz; i += 384) ws[blockIdx.x * nz + i] = 0.f;
    if (blockIdx.x != 0) return;

    if (tid < SS*VV){
        int s = tid/VV, w = tid%VV;
        float sum = 0.f;
        for (int v=0; v<VV; ++v){ float p = PA[s*VV*VV + v*VV + w]; sum = fmaf(p,p,sum); }
        inv[s][w] = 1.f/(sqrtf(sum)+1e-4f);
    }
    __syncthreads();
    {   // A-hat 32x32 B-fragments: fid = s*2+ksv (6 frags x 64 lanes = 384 threads)
        int fid = tid >> 6, lane = tid & 63;
        int s = fid >> 1, ksv = fid & 1;
        int w = lane & 31, h = lane >> 5;
        int v0 = 16*ksv + 8*h;
        short8v vals;
        #pragma unroll
        for (int j=0;j<8;++j){
            int v = v0 + j;
            float f = (v<VV && w<VV) ? PA[s*VV*VV + v*VV + w]*inv[s][w] : 0.f;
            vals[j] = (short)f2bf(f);
        }
        *(short8v*)((char*)ws + AFA_BYTES + (size_t)(fid*64 + lane)*16) = vals;
    }
    // Wc 32x32 A-fragments: fid = ((s*2+ot)*4+ks), 24 frags
    for (int fid4 = tid; fid4 < SS*2*4*64; fid4 += 384){
        int lane = fid4 & 63;
        int ks = (fid4 >> 6) & 3;
        int ot = (fid4 >> 8) & 1;
        int s  = fid4 >> 9;
        int o  = 32*ot + (lane & 31);
        int c0 = 16*ks + 8*(lane >> 5);
        short8v vals;
        #pragma unroll
        for (int j=0;j<8;++j) vals[j] = (short)f2bf(Wc[((size_t)s*CC + o)*CC + c0 + j]);
        *(short8v*)((char*)ws + WCF_BYTES + (size_t)fid4*16) = vals;
    }
}

template<bool YB>
__global__ __launch_bounds__(256,4) void gcn_main_kernel(
    const float* __restrict__ x, float* __restrict__ ws,
    float* __restrict__ yf32, __hip_bfloat16* __restrict__ ybf)
{
    // ONLY LDS: 12.8 KB y tile [o][100] bf16 (epilogue only)
    __shared__ __align__(16) unsigned short lds[CC*100];

    const int tid  = threadIdx.x;
    const int lane = tid & 63;
    const int wv   = tid >> 6;                 // wave owns t = t0 + wv
    const int l31  = lane & 31, h = lane >> 5;
    const bool hi  = (lane >= 32);
    (void)hi;
    // XCD-aware bijective swizzle (T1): 4800 = 8*600, (bid&7)*600 + bid>>3
    const int tile = (blockIdx.x & 7) * (TILES/8) + (blockIdx.x >> 3);
    const int n    = tile / TBLK;
    const int t0   = (tile % TBLK) * TB;
    const int t    = t0 + wv;

    // x A-fragments (32x32x16): rows c = 32mt+l31, k v = 16ksv + 8h + j
    short8v axf[2][2];
    #pragma unroll
    for (int mt=0; mt<2; ++mt){
        #pragma unroll
        for (int ksv=0; ksv<2; ++ksv){
            const int c  = 32*mt + l31;
            const int v0 = 16*ksv + 8*h;
            const float* p = x + ((size_t)(n*CC + c)*TT + t)*VV + v0;
            short8v f;
            if (v0 < 24){
                float4 a = *(const float4*)p;
                float4 b = *(const float4*)(p+4);
                f[0]=(short)f2bf(a.x); f[1]=(short)f2bf(a.y); f[2]=(short)f2bf(a.z); f[3]=(short)f2bf(a.w);
                f[4]=(short)f2bf(b.x); f[5]=(short)f2bf(b.y); f[6]=(short)f2bf(b.z); f[7]=(short)f2bf(b.w);
            } else {
                f[0]=(short)f2bf(p[0]);   // v=24 only
                f[1]=0; f[2]=0; f[3]=0; f[4]=0; f[5]=0; f[6]=0; f[7]=0;
            }
            axf[mt][ksv] = f;
        }
    }

    const short8v* afrag = (const short8v*)((const char*)ws + AFA_BYTES);
    const short8v* wfrag = (const short8v*)((const char*)ws + WCF_BYTES);

    f32x16 zf16;
    #pragma unroll
    for (int i=0;i<16;++i) zf16[i] = 0.f;
    f32x16 yacc[2];
    yacc[0] = zf16; yacc[1] = zf16;

    #pragma unroll 1
    for (int s=0; s<SS; ++s){
        short8v aA0 = afrag[(s*2+0)*64 + lane];
        short8v aA1 = afrag[(s*2+1)*64 + lane];

        // stage A: Z[mt] (c=32mt..32mt+31, w) — 2 chained MFMA over v
        unsigned pk[2][4][2];   // [mt][group q][dword]
        #pragma unroll
        for (int mt=0; mt<2; ++mt){
            f32x16 z = __builtin_amdgcn_mfma_f32_32x32x16_bf16(axf[mt][0], aA0, zf16, 0,0,0);
            z = __builtin_amdgcn_mfma_f32_32x32x16_bf16(axf[mt][1], aA1, z, 0,0,0);
            #pragma unroll
            for (int q=0; q<4; ++q)
                packq(z[4*q], z[4*q+1], z[4*q+2], z[4*q+3], pk[mt][q][0], pk[mt][q][1]);
        }

        // transpose via permlane32_swap + stage B (no DS ops)
        #pragma unroll
        for (int mt=0; mt<2; ++mt){
            #pragma unroll
            for (int ksl=0; ksl<2; ++ksl){
                const int ks = 2*mt + ksl;
                unsigned r0d0, r1d0, r0d1, r1d1;
                SWAP32(pk[mt][2*ksl][0],   pk[mt][2*ksl+1][0], r0d0, r1d0);
                SWAP32(pk[mt][2*ksl][1],   pk[mt][2*ksl+1][1], r0d1, r1d1);
                short8v bz = mk8(r0d0, r0d1, r1d0, r1d1);
                #pragma unroll
                for (int ot=0; ot<2; ++ot){
                    short8v wc = wfrag[((s*2+ot)*4+ks)*64 + lane];
                    yacc[ot] = __builtin_amdgcn_mfma_f32_32x32x16_bf16(wc, bz, yacc[ot], 0,0,0);
                }
            }
        }
    }

    // epilogue: y -> LDS tile [o][t_loc*25+w] bf16 (32x32 C/D layout)
    #pragma unroll
    for (int ot=0; ot<2; ++ot){
        #pragma unroll
        for (int r=0; r<16; ++r){
            const int o = 32*ot + (r&3) + 8*(r>>2) + 4*h;
            if (l31 < VV)
                lds[o*100 + wv*25 + l31] = f2bf(yacc[ot][r]);
        }
    }
    __syncthreads();

    // coalesced global store: 64 rows x 200 B, thread-linear uint2
    // (conv bias cancels through training-mode BN — omitted)
    for (int i = tid; i < 1600; i += 256){
        const int row = i / 25;          // o
        const int c8  = i % 25;          // 4-short grain within 100 cols
        uint2 d = *(const uint2*)&lds[row*100 + c8*4];
        const size_t base = (size_t)(n*CC + row)*(TT*VV) + (size_t)t0*VV + c8*4;
        if (YB){
            *(uint2*)((unsigned short*)ybf + base) = d;
        } else {
            float4 f;
            f.x = bf2f((unsigned short)(d.x & 0xffff));
            f.y = bf2f((unsigned short)(d.x >> 16));
            f.z = bf2f((unsigned short)(d.y & 0xffff));
            f.w = bf2f((unsigned short)(d.y >> 16));
            *(float4*)(yf32 + base) = f;
        }
    }

    // fused stats: thread (o = tid>>2, q = tid&3) reads b64 grains q, q+4, ...
    {
        const int o = tid >> 2, q = tid & 3;
        float s1 = 0.f, s2 = 0.f;
        for (int gr = q; gr < 25; gr += 4){
            uint2 d = *(const uint2*)&lds[o*100 + gr*4];
            float a0 = bf2f((unsigned short)(d.x & 0xffff));
            float a1 = bf2f((unsigned short)(d.x >> 16));
            float a2 = bf2f((unsigned short)(d.y & 0xffff));
            float a3 = bf2f((unsigned short)(d.y >> 16));
            s1 += (a0+a1)+(a2+a3);
            s2 = fmaf(a0,a0,fmaf(a1,a1,fmaf(a2,a2,fmaf(a3,a3,s2))));
        }
        s1 += __shfl_xor(s1,1); s1 += __shfl_xor(s1,2);
        s2 += __shfl_xor(s2,1); s2 += __shfl_xor(s2,2);
        if (q == 0){
            atomicAdd(&ws[n*128 + o],      s1);
            atomicAdd(&ws[n*128 + 64 + o], s2);
        }
    }
}

// bn_relu with fused per-block BN finalize (no separate finalize kernel)
template<bool YB>
__global__ __launch_bounds__(256) void gcn_bn_relu_kernel(
    const float* __restrict__ x, float* __restrict__ out,
    const float* __restrict__ ws, const unsigned short* __restrict__ ybf,
    const float* __restrict__ gamma, const float* __restrict__ beta)
{
    __shared__ float lf[128];   // [o] scale, [64+o] shift
    const int tid = threadIdx.x;
    {
        const int o = tid >> 2, q = tid & 3;
        float s = 0.f, sq = 0.f;
        for (int nn = q*16; nn < q*16 + 16; ++nn){
            s  += ws[nn*128 + o];
            sq += ws[nn*128 + 64 + o];
        }
        s  += __shfl_xor(s,1);  s  += __shfl_xor(s,2);
        sq += __shfl_xor(sq,1); sq += __shfl_xor(sq,2);
        if (q == 0){
            const float mean = s / CNTF;
            const float var  = sq / CNTF - mean*mean;
            const float sc   = gamma[o] * rsqrtf(var + 1e-5f);
            lf[o]      = sc;
            lf[64 + o] = beta[o] - mean*sc;
        }
    }
    __syncthreads();

    for (int i = blockIdx.x * 256 + tid; i < TOTAL4; i += gridDim.x * 256) {
        const int c = (i / PERC4) & (CC - 1);
        const float sc = lf[c];
        const float sh = lf[64 + c];
        float4 yv;
        if (YB){
            uu2 yb = __builtin_nontemporal_load((const uu2*)ybf + i);  // stream-once
            yv.x = bf2f((unsigned short)(yb[0] & 0xffff));
            yv.y = bf2f((unsigned short)(yb[0] >> 16));
            yv.z = bf2f((unsigned short)(yb[1] & 0xffff));
            yv.w = bf2f((unsigned short)(yb[1] >> 16));
        } else {
            yv = reinterpret_cast<float4*>(out)[i];
        }
        float4 xv = reinterpret_cast<const float4*>(x)[i];
        f32x4 r;
        r[0] = fmaxf(fmaf(yv.x, sc, sh) + xv.x, 0.f);
        r[1] = fmaxf(fmaf(yv.y, sc, sh) + xv.y, 0.f);
        r[2] = fmaxf(fmaf(yv.z, sc, sh) + xv.z, 0.f);
        r[3] = fmaxf(fmaf(yv.w, sc, sh) + xv.w, 0.f);
        // out is never re-read: bypass L2/L3 to preserve residency for x/ybf reads
        __builtin_nontemporal_store(r, (f32x4*)out + i);
    }
}

extern "C" void kernel_launch(void* const* d_in, const int* in_sizes, int n_in,
                              void* d_out, int out_size, void* d_ws, size_t ws_size,
                              hipStream_t stream)
{
    const float* x     = (const float*)d_in[0];
    const float* PA    = (const float*)d_in[1];
    const float* Wc    = (const float*)d_in[2];
    const float* gamma = (const float*)d_in[4];
    const float* beta  = (const float*)d_in[5];
    float* out = (float*)d_out;
    float* ws  = (float*)d_ws;

    const size_t ybytes = (size_t)NB*CC*TT*VV*2;
    const bool yb = ws_size >= (size_t)YOFF_BYTES + ybytes;
    __hip_bfloat16* ybf = (__hip_bfloat16*)((char*)d_ws + YOFF_BYTES);

    gcn_prep<<<8, 384, 0, stream>>>(PA, Wc, ws);
    if (yb){
        gcn_main_kernel<true><<<TILES, 256, 0, stream>>>(x, ws, out, ybf);
        gcn_bn_relu_kernel<true><<<4096, 256, 0, stream>>>(x, out, ws, (const unsigned short*)ybf, gamma, beta);
    } else {
        gcn_main_kernel<false><<<TILES, 256, 0, stream>>>(x, ws, out, ybf);
        gcn_bn_relu_kernel<false><<<4096, 256, 0, stream>>>(x, out, ws, (const unsigned short*)ybf, gamma, beta);
    }
}